// Round 4
// baseline (138.931 us; speedup 1.0000x reference)
//
#include <hip/hip_runtime.h>
#include <hip/hip_bf16.h>

#define NSEQ 4096
#define DH 64
#define NBH 32
#define LOG32 3.4657359028f
#define QSCALE 0.125f

typedef unsigned short us8 __attribute__((ext_vector_type(8)));
typedef __bf16 bf16x8 __attribute__((ext_vector_type(8)));
typedef float f32x4 __attribute__((ext_vector_type(4)));

__device__ __forceinline__ unsigned short f2b(float x) {
    __bf16 h = (__bf16)x;                       // native RNE cvt on gfx950
    return __builtin_bit_cast(unsigned short, h);
}
__device__ __forceinline__ bf16x8 cvt8(float4 a, float4 b) {
    us8 u;
    u[0] = f2b(a.x); u[1] = f2b(a.y); u[2] = f2b(a.z); u[3] = f2b(a.w);
    u[4] = f2b(b.x); u[5] = f2b(b.y); u[6] = f2b(b.z); u[7] = f2b(b.w);
    return __builtin_bit_cast(bf16x8, u);
}

// ---------------- kernel 1: LSH hash (Gray-coded bucket per row) ----------------
// 1024 blocks x 256 thr, 1 row/thread: jobs [ch(2)][bh(32)][i(4096)]
__global__ __launch_bounds__(256) void hash_kernel(const float* __restrict__ qkv,
                                                   const float* __restrict__ proj,
                                                   unsigned short* __restrict__ hsh) {
    __shared__ float pdT[512];            // transposed proj: pdT[r*64+d]
    int tid = threadIdx.x;
    for (int j = tid; j < 512; j += 256) pdT[j] = proj[(j & 63) * 8 + (j >> 6)];
    __syncthreads();
    int j = blockIdx.x * 256 + tid;       // [0, 262144)
    int ch = j >> 17;                     // 0=q, 1=k
    int bh = (j >> 12) & 31;
    int i = j & 4095;
    int b = bh >> 4, h = bh & 15;
    const float4* src = (const float4*)(qkv + ((size_t)((b * NSEQ + i) * 3 + ch)) * 1024 + h * 64);
    double acc[8] = {0, 0, 0, 0, 0, 0, 0, 0};
    for (int d4 = 0; d4 < 16; ++d4) {
        float4 x = src[d4];
        double xx = x.x, xy = x.y, xz = x.z, xw = x.w;
        #pragma unroll
        for (int r = 0; r < 8; ++r) {
            const float4 p = *(const float4*)&pdT[r * 64 + d4 * 4];
            acc[r] += xx * p.x + xy * p.y + xz * p.z + xw * p.w;
        }
    }
    int c = 0;
    #pragma unroll
    for (int r = 0; r < 8; ++r)
        if (acc[r] > 0.0) c |= (1 << r);
    hsh[j] = (unsigned short)(c ^ (c >> 1));
}

// ---------------- kernel 2: stable counting sort per (channel, b, h) ----------------
// grid 64 = [pass(2)][bh(32)]; 1024 threads; ballot-ranked, parallel scatter
__global__ __launch_bounds__(1024) void sort_kernel(const unsigned short* __restrict__ hsh,
                                                    int* __restrict__ qidx,
                                                    int* __restrict__ kidx) {
    int blk = blockIdx.x;
    int pass = blk >> 5, bh = blk & 31;
    const unsigned short* src = hsh + pass * 131072 + bh * 4096;
    int* outg = (pass ? kidx : qidx) + bh * 4096;
    int tid = threadIdx.x;
    int wv = tid >> 6, ln = tid & 63;
    __shared__ int hist[64][256];          // 64 KB
    __shared__ unsigned char rnk[4096];
    __shared__ unsigned char bkt[4096];
    __shared__ int base[256];
    for (int jj = tid; jj < 64 * 256; jj += 1024) (&hist[0][0])[jj] = 0;
    __syncthreads();
    // each wave ranks 4 segments of 64 elements
    for (int s = wv; s < 64; s += 16) {
        int i = s * 64 + ln;
        int q = src[i];
        bkt[i] = (unsigned char)q;
        unsigned long long mask = ~0ULL;
        #pragma unroll
        for (int bit = 0; bit < 8; ++bit) {
            unsigned long long bb = __ballot((q >> bit) & 1);
            mask &= ((q >> bit) & 1) ? bb : ~bb;
        }
        int r = __popcll(mask & ((1ULL << ln) - 1ULL));
        rnk[i] = (unsigned char)r;
        if (r == 0) hist[s][q] = __popcll(mask);
    }
    __syncthreads();
    // per-bucket prefix over segments + bucket totals
    int cnt_tot = 0;
    if (tid < 256) {
        int tot = 0;
        #pragma unroll 8
        for (int s = 0; s < 64; ++s) { int c = hist[s][tid]; hist[s][tid] = tot; tot += c; }
        base[tid] = tot;
        cnt_tot = tot;
    }
    __syncthreads();
    // Hillis-Steele inclusive scan over 256 bucket totals
    for (int off = 1; off < 256; off <<= 1) {
        int t = (tid >= off && tid < 256) ? base[tid - off] : 0;
        __syncthreads();
        if (tid >= off && tid < 256) base[tid] += t;
        __syncthreads();
    }
    int incl = 0;
    if (tid < 256) incl = base[tid];
    __syncthreads();
    if (tid < 256) base[tid] = incl - cnt_tot;   // exclusive global base
    __syncthreads();
    // fully parallel stable scatter
    for (int i = tid; i < 4096; i += 1024) {
        int q = bkt[i];
        outg[base[q] + hist[i >> 6][q] + rnk[i]] = i;
    }
}

// ---------------- kernel 3: fused block-diag + residual attention ----------------
// grid: 1024 = [bh(32)][g(32)]; 512 threads (8 waves); 3 blocks/CU (LDS 50.5 KB)
__global__ __launch_bounds__(512, 6) void attn_kernel(const float* __restrict__ qkv,
                                                      const int* __restrict__ sampled,
                                                      const int* __restrict__ qidx_g,
                                                      const int* __restrict__ kidx_g,
                                                      float* __restrict__ out) {
    int gb = blockIdx.x;
    int bh = gb >> 5, g = gb & 31;
    int b = bh >> 4, h = bh & 15;
    int tid = threadIdx.x;
    int w = tid >> 6, l = tid & 63;
    int l15 = l & 15, lq = l >> 4;

    // KP: phase1 = K [256 rows][8 chunks], later = P half [128 rows][16 chunks]
    __shared__ us8 KP[2048];                 // 32 KB
    __shared__ us8 VT[1024];                 // 16 KB: V^T [64 dims][16 chunks] (128 keys)
    __shared__ float colbias[256];
    __shared__ int qrow[128];
    __shared__ int krow[256];

    // ---- index staging ----
    if (tid < 128) {
        qrow[tid] = qidx_g[bh * NSEQ + g * 128 + tid];
        krow[tid] = kidx_g[bh * NSEQ + g * 128 + tid];
        colbias[tid] = 0.0f;
    } else if (tid < 256) {
        int j = tid - 128;
        int sp = sampled[bh * 128 + j];
        krow[tid] = kidx_g[bh * NSEQ + sp];
        colbias[tid] = ((sp >> 7) == g) ? -1e30f : LOG32;
    }
    __syncthreads();

    // ---- Q fragments straight from global (this wave's 16 rows) ----
    int qr = qrow[w * 16 + l15];
    const float* qbase = qkv + ((size_t)((b * NSEQ + qr) * 3 + 0)) * 1024 + h * 64 + lq * 8;
    float4 qa0 = *(const float4*)(qbase);
    float4 qa1 = *(const float4*)(qbase + 4);
    float4 qb0 = *(const float4*)(qbase + 32);
    float4 qb1 = *(const float4*)(qbase + 36);

    // ---- V-hi (keys 128..255) issued EARLY into registers; written to LDS after PV1 ----
    int vkey = tid >> 2, vqd = tid & 3;     // 4 threads per key, 16 dims each
    const float4* vhisrc = (const float4*)(qkv + ((size_t)((b * NSEQ + krow[128 + vkey]) * 3 + 2)) * 1024 + h * 64 + vqd * 16);
    float4 vh0 = vhisrc[0], vh1 = vhisrc[1], vh2 = vhisrc[2], vh3 = vhisrc[3];

    // ---- stage K (256 rows x 64) into KP, swizzled ----
    #pragma unroll
    for (int rep = 0; rep < 2; ++rep) {
        int job = tid + rep * 512;
        int r = job >> 2, qt = job & 3;
        const float4* src = (const float4*)(qkv + ((size_t)((b * NSEQ + krow[r]) * 3 + 1)) * 1024 + h * 64 + qt * 16);
        float4 f0 = src[0], f1 = src[1], f2 = src[2], f3 = src[3];
        us8 u0 = __builtin_bit_cast(us8, cvt8(f0, f1));
        us8 u1 = __builtin_bit_cast(us8, cvt8(f2, f3));
        KP[r * 8 + ((qt * 2) ^ (r & 7))] = u0;
        KP[r * 8 + ((qt * 2 + 1) ^ (r & 7))] = u1;
    }
    // ---- stage V-lo transposed (keys 0..127; 4 threads/key, 16 dims each) ----
    {
        const float4* src = (const float4*)(qkv + ((size_t)((b * NSEQ + krow[vkey]) * 3 + 2)) * 1024 + h * 64 + vqd * 16);
        float4 f0 = src[0], f1 = src[1], f2 = src[2], f3 = src[3];
        float vals[16] = {f0.x, f0.y, f0.z, f0.w, f1.x, f1.y, f1.z, f1.w,
                          f2.x, f2.y, f2.z, f2.w, f3.x, f3.y, f3.z, f3.w};
        unsigned short* vt_us = (unsigned short*)VT;
        int kc8 = vkey >> 3, ke = vkey & 7;
        #pragma unroll
        for (int t = 0; t < 16; ++t) {
            int d = vqd * 16 + t;
            vt_us[((d * 16 + (kc8 ^ (d & 7))) << 3) + ke] = f2b(vals[t]);
        }
    }
    __syncthreads();

    // ---- phase 1: S = Q K^T * scale + bias, scores stay in registers ----
    bf16x8 a0 = cvt8(qa0, qa1);
    bf16x8 a1 = cvt8(qb0, qb1);
    f32x4 sreg[16];
    #pragma unroll
    for (int ct = 0; ct < 16; ++ct) {
        int kr = ct * 16 + l15;
        bf16x8 b0 = __builtin_bit_cast(bf16x8, KP[kr * 8 + (lq ^ (kr & 7))]);
        bf16x8 b1 = __builtin_bit_cast(bf16x8, KP[kr * 8 + ((lq + 4) ^ (kr & 7))]);
        f32x4 acc = {0.f, 0.f, 0.f, 0.f};
        acc = __builtin_amdgcn_mfma_f32_16x16x32_bf16(a0, b0, acc, 0, 0, 0);
        acc = __builtin_amdgcn_mfma_f32_16x16x32_bf16(a1, b1, acc, 0, 0, 0);
        float cb = colbias[kr];
        #pragma unroll
        for (int j = 0; j < 4; ++j) sreg[ct][j] = acc[j] * QSCALE + cb;
    }

    // ---- phase 2: softmax fully in registers ----
    float m0 = -1e30f, m1 = -1e30f, m2 = -1e30f, m3 = -1e30f;
    #pragma unroll
    for (int ct = 0; ct < 16; ++ct) {
        m0 = fmaxf(m0, sreg[ct][0]); m1 = fmaxf(m1, sreg[ct][1]);
        m2 = fmaxf(m2, sreg[ct][2]); m3 = fmaxf(m3, sreg[ct][3]);
    }
    #pragma unroll
    for (int mask = 1; mask < 16; mask <<= 1) {
        m0 = fmaxf(m0, __shfl_xor(m0, mask));
        m1 = fmaxf(m1, __shfl_xor(m1, mask));
        m2 = fmaxf(m2, __shfl_xor(m2, mask));
        m3 = fmaxf(m3, __shfl_xor(m3, mask));
    }
    float s0 = 0.f, s1 = 0.f, s2 = 0.f, s3 = 0.f;
    #pragma unroll
    for (int ct = 0; ct < 16; ++ct) {
        float p0 = __expf(sreg[ct][0] - m0); sreg[ct][0] = p0; s0 += p0;
        float p1 = __expf(sreg[ct][1] - m1); sreg[ct][1] = p1; s1 += p1;
        float p2 = __expf(sreg[ct][2] - m2); sreg[ct][2] = p2; s2 += p2;
        float p3 = __expf(sreg[ct][3] - m3); sreg[ct][3] = p3; s3 += p3;
    }
    #pragma unroll
    for (int mask = 1; mask < 16; mask <<= 1) {
        s0 += __shfl_xor(s0, mask);
        s1 += __shfl_xor(s1, mask);
        s2 += __shfl_xor(s2, mask);
        s3 += __shfl_xor(s3, mask);
    }
    float rs0 = 1.f / s0, rs1 = 1.f / s1, rs2 = 1.f / s2, rs3 = 1.f / s3;

    __syncthreads();   // all waves done reading K from KP

    unsigned short* pp = (unsigned short*)KP;
    int wrow0 = w * 16 + lq * 4;
    // ---- write P-lo (cols 0..127) over KP ----
    #pragma unroll
    for (int ct = 0; ct < 8; ++ct) {
        int c8 = 2 * ct + (l15 >> 3), ce = l15 & 7;
        #pragma unroll
        for (int j = 0; j < 4; ++j) {
            int row = wrow0 + j;
            pp[((row * 16 + (c8 ^ (row & 7))) << 3) + ce] = f2b(sreg[ct][j]);
        }
    }
    __syncthreads();

    f32x4 oacc[4] = {{0.f,0.f,0.f,0.f},{0.f,0.f,0.f,0.f},{0.f,0.f,0.f,0.f},{0.f,0.f,0.f,0.f}};
    int prow = w * 16 + l15;
    // ---- PV pass 1 (keys 0..127) ----
    #pragma unroll
    for (int ks = 0; ks < 4; ++ks) {
        bf16x8 pa = __builtin_bit_cast(bf16x8, KP[prow * 16 + ((ks * 4 + lq) ^ (prow & 7))]);
        #pragma unroll
        for (int ct = 0; ct < 4; ++ct) {
            int d = ct * 16 + l15;
            bf16x8 vb = __builtin_bit_cast(bf16x8, VT[d * 16 + ((ks * 4 + lq) ^ (d & 7))]);
            oacc[ct] = __builtin_amdgcn_mfma_f32_16x16x32_bf16(pa, vb, oacc[ct], 0, 0, 0);
        }
    }
    __syncthreads();   // P-lo and V-lo dead
    // ---- write P-hi (cols 128..255) over KP; write V-hi (regs) into VT ----
    #pragma unroll
    for (int ct = 8; ct < 16; ++ct) {
        int c8 = 2 * (ct - 8) + (l15 >> 3), ce = l15 & 7;
        #pragma unroll
        for (int j = 0; j < 4; ++j) {
            int row = wrow0 + j;
            pp[((row * 16 + (c8 ^ (row & 7))) << 3) + ce] = f2b(sreg[ct][j]);
        }
    }
    {
        float vals[16] = {vh0.x, vh0.y, vh0.z, vh0.w, vh1.x, vh1.y, vh1.z, vh1.w,
                          vh2.x, vh2.y, vh2.z, vh2.w, vh3.x, vh3.y, vh3.z, vh3.w};
        unsigned short* vt_us = (unsigned short*)VT;
        int kc8 = vkey >> 3, ke = vkey & 7;
        #pragma unroll
        for (int t = 0; t < 16; ++t) {
            int d = vqd * 16 + t;
            vt_us[((d * 16 + (kc8 ^ (d & 7))) << 3) + ke] = f2b(vals[t]);
        }
    }
    __syncthreads();
    // ---- PV pass 2 (keys 128..255) ----
    #pragma unroll
    for (int ks = 4; ks < 8; ++ks) {
        bf16x8 pa = __builtin_bit_cast(bf16x8, KP[prow * 16 + (((ks - 4) * 4 + lq) ^ (prow & 7))]);
        #pragma unroll
        for (int ct = 0; ct < 4; ++ct) {
            int d = ct * 16 + l15;
            bf16x8 vb = __builtin_bit_cast(bf16x8, VT[d * 16 + (((ks - 4) * 4 + lq) ^ (d & 7))]);
            oacc[ct] = __builtin_amdgcn_mfma_f32_16x16x32_bf16(pa, vb, oacc[ct], 0, 0, 0);
        }
    }

    // ---- epilogue: normalize + scatter to original query positions ----
    float rs[4] = {rs0, rs1, rs2, rs3};
    #pragma unroll
    for (int j = 0; j < 4; ++j) {
        int row = wrow0 + j;
        size_t obase = ((size_t)((b * NSEQ + qrow[row]) * 16 + h)) * 64;
        #pragma unroll
        for (int ct = 0; ct < 4; ++ct)
            out[obase + ct * 16 + l15] = oacc[ct][j] * rs[j];
    }
}

extern "C" void kernel_launch(void* const* d_in, const int* in_sizes, int n_in,
                              void* d_out, int out_size, void* d_ws, size_t ws_size,
                              hipStream_t stream) {
    const float* qkv = (const float*)d_in[0];      // [2,4096,3,16,64] f32
    const float* proj = (const float*)d_in[1];     // [64,8] f32
    const int* sampled = (const int*)d_in[2];      // [2,16,128] i32
    float* outp = (float*)d_out;                   // [2,4096,16,64] f32

    int* qidx = (int*)d_ws;
    int* kidx = qidx + NBH * NSEQ;
    unsigned short* hsh = (unsigned short*)(kidx + NBH * NSEQ);

    hash_kernel<<<1024, 256, 0, stream>>>(qkv, proj, hsh);
    sort_kernel<<<64, 1024, 0, stream>>>(hsh, qidx, kidx);
    attn_kernel<<<NBH * 32, 512, 0, stream>>>(qkv, sampled, qidx, kidx, outp);
}

// Round 5
// 89.548 us; speedup vs baseline: 1.5515x; 1.5515x over previous
//
#include <hip/hip_runtime.h>
#include <hip/hip_bf16.h>

#define NSEQ 4096
#define DH 64
#define NBH 32
#define LOG32 3.4657359028f
#define QSCALE 0.125f

typedef unsigned short us8 __attribute__((ext_vector_type(8)));
typedef __bf16 bf16x8 __attribute__((ext_vector_type(8)));
typedef float f32x4 __attribute__((ext_vector_type(4)));

__device__ __forceinline__ unsigned short f2b(float x) {
    __bf16 h = (__bf16)x;                       // native RNE cvt on gfx950
    return __builtin_bit_cast(unsigned short, h);
}
__device__ __forceinline__ bf16x8 cvt8(float4 a, float4 b) {
    us8 u;
    u[0] = f2b(a.x); u[1] = f2b(a.y); u[2] = f2b(a.z); u[3] = f2b(a.w);
    u[4] = f2b(b.x); u[5] = f2b(b.y); u[6] = f2b(b.z); u[7] = f2b(b.w);
    return __builtin_bit_cast(bf16x8, u);
}

// ---------------- kernel 1: LSH hash (Gray-coded bucket per row) ----------------
// 1024 blocks x 256 thr, 1 row/thread: jobs [ch(2)][bh(32)][i(4096)]
__global__ __launch_bounds__(256) void hash_kernel(const float* __restrict__ qkv,
                                                   const float* __restrict__ proj,
                                                   unsigned short* __restrict__ hsh) {
    __shared__ float pdT[512];            // transposed proj: pdT[r*64+d]
    int tid = threadIdx.x;
    for (int j = tid; j < 512; j += 256) pdT[j] = proj[(j & 63) * 8 + (j >> 6)];
    __syncthreads();
    int j = blockIdx.x * 256 + tid;       // [0, 262144)
    int ch = j >> 17;                     // 0=q, 1=k
    int bh = (j >> 12) & 31;
    int i = j & 4095;
    int b = bh >> 4, h = bh & 15;
    const float4* src = (const float4*)(qkv + ((size_t)((b * NSEQ + i) * 3 + ch)) * 1024 + h * 64);
    double acc[8] = {0, 0, 0, 0, 0, 0, 0, 0};
    for (int d4 = 0; d4 < 16; ++d4) {
        float4 x = src[d4];
        double xx = x.x, xy = x.y, xz = x.z, xw = x.w;
        #pragma unroll
        for (int r = 0; r < 8; ++r) {
            const float4 p = *(const float4*)&pdT[r * 64 + d4 * 4];
            acc[r] += xx * p.x + xy * p.y + xz * p.z + xw * p.w;
        }
    }
    int c = 0;
    #pragma unroll
    for (int r = 0; r < 8; ++r)
        if (acc[r] > 0.0) c |= (1 << r);
    hsh[j] = (unsigned short)(c ^ (c >> 1));
}

// ---------------- kernel 2: stable counting sort per (channel, b, h) ----------------
// grid 64 = [pass(2)][bh(32)]; 1024 threads; ballot-ranked, parallel scatter
__global__ __launch_bounds__(1024) void sort_kernel(const unsigned short* __restrict__ hsh,
                                                    int* __restrict__ qidx,
                                                    int* __restrict__ kidx) {
    int blk = blockIdx.x;
    int pass = blk >> 5, bh = blk & 31;
    const unsigned short* src = hsh + pass * 131072 + bh * 4096;
    int* outg = (pass ? kidx : qidx) + bh * 4096;
    int tid = threadIdx.x;
    int wv = tid >> 6, ln = tid & 63;
    __shared__ int hist[64][256];          // 64 KB
    __shared__ unsigned char rnk[4096];
    __shared__ unsigned char bkt[4096];
    __shared__ int base[256];
    for (int jj = tid; jj < 64 * 256; jj += 1024) (&hist[0][0])[jj] = 0;
    __syncthreads();
    // each wave ranks 4 segments of 64 elements
    for (int s = wv; s < 64; s += 16) {
        int i = s * 64 + ln;
        int q = src[i];
        bkt[i] = (unsigned char)q;
        unsigned long long mask = ~0ULL;
        #pragma unroll
        for (int bit = 0; bit < 8; ++bit) {
            unsigned long long bb = __ballot((q >> bit) & 1);
            mask &= ((q >> bit) & 1) ? bb : ~bb;
        }
        int r = __popcll(mask & ((1ULL << ln) - 1ULL));
        rnk[i] = (unsigned char)r;
        if (r == 0) hist[s][q] = __popcll(mask);
    }
    __syncthreads();
    // per-bucket prefix over segments + bucket totals
    int cnt_tot = 0;
    if (tid < 256) {
        int tot = 0;
        #pragma unroll 8
        for (int s = 0; s < 64; ++s) { int c = hist[s][tid]; hist[s][tid] = tot; tot += c; }
        base[tid] = tot;
        cnt_tot = tot;
    }
    __syncthreads();
    // Hillis-Steele inclusive scan over 256 bucket totals
    for (int off = 1; off < 256; off <<= 1) {
        int t = (tid >= off && tid < 256) ? base[tid - off] : 0;
        __syncthreads();
        if (tid >= off && tid < 256) base[tid] += t;
        __syncthreads();
    }
    int incl = 0;
    if (tid < 256) incl = base[tid];
    __syncthreads();
    if (tid < 256) base[tid] = incl - cnt_tot;   // exclusive global base
    __syncthreads();
    // fully parallel stable scatter
    for (int i = tid; i < 4096; i += 1024) {
        int q = bkt[i];
        outg[base[q] + hist[i >> 6][q] + rnk[i]] = i;
    }
}

// ---------------- kernel 3: fused block-diag + residual attention ----------------
// grid: 1024 = [bh(32)][g(32)]; 512 threads (8 waves)
// launch_bounds (512,4): 128-VGPR budget — (512,6) spilled sreg to scratch (R4: FETCH +81MB)
__global__ __launch_bounds__(512, 4) void attn_kernel(const float* __restrict__ qkv,
                                                      const int* __restrict__ sampled,
                                                      const int* __restrict__ qidx_g,
                                                      const int* __restrict__ kidx_g,
                                                      float* __restrict__ out) {
    int gb = blockIdx.x;
    int bh = gb >> 5, g = gb & 31;
    int b = bh >> 4, h = bh & 15;
    int tid = threadIdx.x;
    int w = tid >> 6, l = tid & 63;
    int l15 = l & 15, lq = l >> 4;

    // KP: phase1 = K [256 rows][8 chunks], later = P half [128 rows][16 chunks]
    __shared__ us8 KP[2048];                 // 32 KB
    __shared__ us8 VT[1024];                 // 16 KB: V^T [64 dims][16 chunks] (128 keys)
    __shared__ float colbias[256];
    __shared__ int qrow[128];
    __shared__ int krow[256];

    // ---- index staging ----
    if (tid < 128) {
        qrow[tid] = qidx_g[bh * NSEQ + g * 128 + tid];
        krow[tid] = kidx_g[bh * NSEQ + g * 128 + tid];
        colbias[tid] = 0.0f;
    } else if (tid < 256) {
        int j = tid - 128;
        int sp = sampled[bh * 128 + j];
        krow[tid] = kidx_g[bh * NSEQ + sp];
        colbias[tid] = ((sp >> 7) == g) ? -1e30f : LOG32;
    }
    __syncthreads();

    // ---- Q fragments straight from global (this wave's 16 rows) ----
    int qr = qrow[w * 16 + l15];
    const float* qbase = qkv + ((size_t)((b * NSEQ + qr) * 3 + 0)) * 1024 + h * 64 + lq * 8;
    float4 qa0 = *(const float4*)(qbase);
    float4 qa1 = *(const float4*)(qbase + 4);
    float4 qb0 = *(const float4*)(qbase + 32);
    float4 qb1 = *(const float4*)(qbase + 36);

    // ---- V-hi (keys 128..255) issued EARLY into registers; written to LDS after PV1 ----
    int vkey = tid >> 2, vqd = tid & 3;     // 4 threads per key, 16 dims each
    const float4* vhisrc = (const float4*)(qkv + ((size_t)((b * NSEQ + krow[128 + vkey]) * 3 + 2)) * 1024 + h * 64 + vqd * 16);
    float4 vh0 = vhisrc[0], vh1 = vhisrc[1], vh2 = vhisrc[2], vh3 = vhisrc[3];

    // ---- stage K (256 rows x 64) into KP, swizzled ----
    #pragma unroll
    for (int rep = 0; rep < 2; ++rep) {
        int job = tid + rep * 512;
        int r = job >> 2, qt = job & 3;
        const float4* src = (const float4*)(qkv + ((size_t)((b * NSEQ + krow[r]) * 3 + 1)) * 1024 + h * 64 + qt * 16);
        float4 f0 = src[0], f1 = src[1], f2 = src[2], f3 = src[3];
        us8 u0 = __builtin_bit_cast(us8, cvt8(f0, f1));
        us8 u1 = __builtin_bit_cast(us8, cvt8(f2, f3));
        KP[r * 8 + ((qt * 2) ^ (r & 7))] = u0;
        KP[r * 8 + ((qt * 2 + 1) ^ (r & 7))] = u1;
    }
    // ---- stage V-lo transposed (keys 0..127; 4 threads/key, 16 dims each) ----
    {
        const float4* src = (const float4*)(qkv + ((size_t)((b * NSEQ + krow[vkey]) * 3 + 2)) * 1024 + h * 64 + vqd * 16);
        float4 f0 = src[0], f1 = src[1], f2 = src[2], f3 = src[3];
        float vals[16] = {f0.x, f0.y, f0.z, f0.w, f1.x, f1.y, f1.z, f1.w,
                          f2.x, f2.y, f2.z, f2.w, f3.x, f3.y, f3.z, f3.w};
        unsigned short* vt_us = (unsigned short*)VT;
        int kc8 = vkey >> 3, ke = vkey & 7;
        #pragma unroll
        for (int t = 0; t < 16; ++t) {
            int d = vqd * 16 + t;
            vt_us[((d * 16 + (kc8 ^ (d & 7))) << 3) + ke] = f2b(vals[t]);
        }
    }
    __syncthreads();

    // ---- phase 1: S = Q K^T * scale + bias, scores stay in registers ----
    bf16x8 a0 = cvt8(qa0, qa1);
    bf16x8 a1 = cvt8(qb0, qb1);
    f32x4 sreg[16];
    #pragma unroll
    for (int ct = 0; ct < 16; ++ct) {
        int kr = ct * 16 + l15;
        bf16x8 b0 = __builtin_bit_cast(bf16x8, KP[kr * 8 + (lq ^ (kr & 7))]);
        bf16x8 b1 = __builtin_bit_cast(bf16x8, KP[kr * 8 + ((lq + 4) ^ (kr & 7))]);
        f32x4 acc = {0.f, 0.f, 0.f, 0.f};
        acc = __builtin_amdgcn_mfma_f32_16x16x32_bf16(a0, b0, acc, 0, 0, 0);
        acc = __builtin_amdgcn_mfma_f32_16x16x32_bf16(a1, b1, acc, 0, 0, 0);
        float cb = colbias[kr];
        #pragma unroll
        for (int j = 0; j < 4; ++j) sreg[ct][j] = acc[j] * QSCALE + cb;
    }

    // ---- phase 2: softmax fully in registers ----
    float m0 = -1e30f, m1 = -1e30f, m2 = -1e30f, m3 = -1e30f;
    #pragma unroll
    for (int ct = 0; ct < 16; ++ct) {
        m0 = fmaxf(m0, sreg[ct][0]); m1 = fmaxf(m1, sreg[ct][1]);
        m2 = fmaxf(m2, sreg[ct][2]); m3 = fmaxf(m3, sreg[ct][3]);
    }
    #pragma unroll
    for (int mask = 1; mask < 16; mask <<= 1) {
        m0 = fmaxf(m0, __shfl_xor(m0, mask));
        m1 = fmaxf(m1, __shfl_xor(m1, mask));
        m2 = fmaxf(m2, __shfl_xor(m2, mask));
        m3 = fmaxf(m3, __shfl_xor(m3, mask));
    }
    float s0 = 0.f, s1 = 0.f, s2 = 0.f, s3 = 0.f;
    #pragma unroll
    for (int ct = 0; ct < 16; ++ct) {
        float p0 = __expf(sreg[ct][0] - m0); sreg[ct][0] = p0; s0 += p0;
        float p1 = __expf(sreg[ct][1] - m1); sreg[ct][1] = p1; s1 += p1;
        float p2 = __expf(sreg[ct][2] - m2); sreg[ct][2] = p2; s2 += p2;
        float p3 = __expf(sreg[ct][3] - m3); sreg[ct][3] = p3; s3 += p3;
    }
    #pragma unroll
    for (int mask = 1; mask < 16; mask <<= 1) {
        s0 += __shfl_xor(s0, mask);
        s1 += __shfl_xor(s1, mask);
        s2 += __shfl_xor(s2, mask);
        s3 += __shfl_xor(s3, mask);
    }
    float rs0 = 1.f / s0, rs1 = 1.f / s1, rs2 = 1.f / s2, rs3 = 1.f / s3;

    __syncthreads();   // all waves done reading K from KP

    unsigned short* pp = (unsigned short*)KP;
    int wrow0 = w * 16 + lq * 4;
    // ---- write P-lo (cols 0..127) over KP ----
    #pragma unroll
    for (int ct = 0; ct < 8; ++ct) {
        int c8 = 2 * ct + (l15 >> 3), ce = l15 & 7;
        #pragma unroll
        for (int j = 0; j < 4; ++j) {
            int row = wrow0 + j;
            pp[((row * 16 + (c8 ^ (row & 7))) << 3) + ce] = f2b(sreg[ct][j]);
        }
    }
    __syncthreads();

    f32x4 oacc[4] = {{0.f,0.f,0.f,0.f},{0.f,0.f,0.f,0.f},{0.f,0.f,0.f,0.f},{0.f,0.f,0.f,0.f}};
    int prow = w * 16 + l15;
    // ---- PV pass 1 (keys 0..127) ----
    #pragma unroll
    for (int ks = 0; ks < 4; ++ks) {
        bf16x8 pa = __builtin_bit_cast(bf16x8, KP[prow * 16 + ((ks * 4 + lq) ^ (prow & 7))]);
        #pragma unroll
        for (int ct = 0; ct < 4; ++ct) {
            int d = ct * 16 + l15;
            bf16x8 vb = __builtin_bit_cast(bf16x8, VT[d * 16 + ((ks * 4 + lq) ^ (d & 7))]);
            oacc[ct] = __builtin_amdgcn_mfma_f32_16x16x32_bf16(pa, vb, oacc[ct], 0, 0, 0);
        }
    }
    __syncthreads();   // P-lo and V-lo dead
    // ---- write P-hi (cols 128..255) over KP; write V-hi (regs) into VT ----
    #pragma unroll
    for (int ct = 8; ct < 16; ++ct) {
        int c8 = 2 * (ct - 8) + (l15 >> 3), ce = l15 & 7;
        #pragma unroll
        for (int j = 0; j < 4; ++j) {
            int row = wrow0 + j;
            pp[((row * 16 + (c8 ^ (row & 7))) << 3) + ce] = f2b(sreg[ct][j]);
        }
    }
    {
        float vals[16] = {vh0.x, vh0.y, vh0.z, vh0.w, vh1.x, vh1.y, vh1.z, vh1.w,
                          vh2.x, vh2.y, vh2.z, vh2.w, vh3.x, vh3.y, vh3.z, vh3.w};
        unsigned short* vt_us = (unsigned short*)VT;
        int kc8 = vkey >> 3, ke = vkey & 7;
        #pragma unroll
        for (int t = 0; t < 16; ++t) {
            int d = vqd * 16 + t;
            vt_us[((d * 16 + (kc8 ^ (d & 7))) << 3) + ke] = f2b(vals[t]);
        }
    }
    __syncthreads();
    // ---- PV pass 2 (keys 128..255) ----
    #pragma unroll
    for (int ks = 4; ks < 8; ++ks) {
        bf16x8 pa = __builtin_bit_cast(bf16x8, KP[prow * 16 + (((ks - 4) * 4 + lq) ^ (prow & 7))]);
        #pragma unroll
        for (int ct = 0; ct < 4; ++ct) {
            int d = ct * 16 + l15;
            bf16x8 vb = __builtin_bit_cast(bf16x8, VT[d * 16 + (((ks - 4) * 4 + lq) ^ (d & 7))]);
            oacc[ct] = __builtin_amdgcn_mfma_f32_16x16x32_bf16(pa, vb, oacc[ct], 0, 0, 0);
        }
    }

    // ---- epilogue: normalize + scatter to original query positions ----
    float rs[4] = {rs0, rs1, rs2, rs3};
    #pragma unroll
    for (int j = 0; j < 4; ++j) {
        int row = wrow0 + j;
        size_t obase = ((size_t)((b * NSEQ + qrow[row]) * 16 + h)) * 64;
        #pragma unroll
        for (int ct = 0; ct < 4; ++ct)
            out[obase + ct * 16 + l15] = oacc[ct][j] * rs[j];
    }
}

extern "C" void kernel_launch(void* const* d_in, const int* in_sizes, int n_in,
                              void* d_out, int out_size, void* d_ws, size_t ws_size,
                              hipStream_t stream) {
    const float* qkv = (const float*)d_in[0];      // [2,4096,3,16,64] f32
    const float* proj = (const float*)d_in[1];     // [64,8] f32
    const int* sampled = (const int*)d_in[2];      // [2,16,128] i32
    float* outp = (float*)d_out;                   // [2,4096,16,64] f32

    int* qidx = (int*)d_ws;
    int* kidx = qidx + NBH * NSEQ;
    unsigned short* hsh = (unsigned short*)(kidx + NBH * NSEQ);

    hash_kernel<<<1024, 256, 0, stream>>>(qkv, proj, hsh);
    sort_kernel<<<64, 1024, 0, stream>>>(hsh, qidx, kidx);
    attn_kernel<<<NBH * 32, 512, 0, stream>>>(qkv, sampled, qidx, kidx, outp);
}

// Round 6
// 87.106 us; speedup vs baseline: 1.5950x; 1.0280x over previous
//
#include <hip/hip_runtime.h>
#include <hip/hip_bf16.h>

#define NSEQ 4096
#define DH 64
#define NBH 32
#define LOG32 3.4657359028f
#define QSCALE 0.125f

typedef unsigned short us8 __attribute__((ext_vector_type(8)));
typedef __bf16 bf16x8 __attribute__((ext_vector_type(8)));
typedef float f32x4 __attribute__((ext_vector_type(4)));

__device__ __forceinline__ unsigned short f2b(float x) {
    __bf16 h = (__bf16)x;                       // native RNE cvt on gfx950
    return __builtin_bit_cast(unsigned short, h);
}
__device__ __forceinline__ bf16x8 cvt8(float4 a, float4 b) {
    us8 u;
    u[0] = f2b(a.x); u[1] = f2b(a.y); u[2] = f2b(a.z); u[3] = f2b(a.w);
    u[4] = f2b(b.x); u[5] = f2b(b.y); u[6] = f2b(b.z); u[7] = f2b(b.w);
    return __builtin_bit_cast(bf16x8, u);
}

// ---------------- kernel 1: LSH hash (Gray-coded bucket per row) ----------------
// 1024 blocks x 256 thr, 1 row/thread: jobs [ch(2)][bh(32)][i(4096)]
__global__ __launch_bounds__(256) void hash_kernel(const float* __restrict__ qkv,
                                                   const float* __restrict__ proj,
                                                   unsigned short* __restrict__ hsh) {
    __shared__ float pdT[512];            // transposed proj: pdT[r*64+d]
    int tid = threadIdx.x;
    for (int j = tid; j < 512; j += 256) pdT[j] = proj[(j & 63) * 8 + (j >> 6)];
    __syncthreads();
    int j = blockIdx.x * 256 + tid;       // [0, 262144)
    int ch = j >> 17;                     // 0=q, 1=k
    int bh = (j >> 12) & 31;
    int i = j & 4095;
    int b = bh >> 4, h = bh & 15;
    const float4* src = (const float4*)(qkv + ((size_t)((b * NSEQ + i) * 3 + ch)) * 1024 + h * 64);
    double acc[8] = {0, 0, 0, 0, 0, 0, 0, 0};
    for (int d4 = 0; d4 < 16; ++d4) {
        float4 x = src[d4];
        double xx = x.x, xy = x.y, xz = x.z, xw = x.w;
        #pragma unroll
        for (int r = 0; r < 8; ++r) {
            const float4 p = *(const float4*)&pdT[r * 64 + d4 * 4];
            acc[r] += xx * p.x + xy * p.y + xz * p.z + xw * p.w;
        }
    }
    int c = 0;
    #pragma unroll
    for (int r = 0; r < 8; ++r)
        if (acc[r] > 0.0) c |= (1 << r);
    hsh[j] = (unsigned short)(c ^ (c >> 1));
}

// ---------------- kernel 2: stable counting sort per (channel, b, h) ----------------
// grid 64 = [pass(2)][bh(32)]; 1024 threads; ballot-ranked, parallel scatter
__global__ __launch_bounds__(1024) void sort_kernel(const unsigned short* __restrict__ hsh,
                                                    int* __restrict__ qidx,
                                                    int* __restrict__ kidx) {
    int blk = blockIdx.x;
    int pass = blk >> 5, bh = blk & 31;
    const unsigned short* src = hsh + pass * 131072 + bh * 4096;
    int* outg = (pass ? kidx : qidx) + bh * 4096;
    int tid = threadIdx.x;
    int wv = tid >> 6, ln = tid & 63;
    __shared__ int hist[64][256];          // 64 KB
    __shared__ unsigned char rnk[4096];
    __shared__ unsigned char bkt[4096];
    __shared__ int base[256];
    for (int jj = tid; jj < 64 * 256; jj += 1024) (&hist[0][0])[jj] = 0;
    __syncthreads();
    // each wave ranks 4 segments of 64 elements
    for (int s = wv; s < 64; s += 16) {
        int i = s * 64 + ln;
        int q = src[i];
        bkt[i] = (unsigned char)q;
        unsigned long long mask = ~0ULL;
        #pragma unroll
        for (int bit = 0; bit < 8; ++bit) {
            unsigned long long bb = __ballot((q >> bit) & 1);
            mask &= ((q >> bit) & 1) ? bb : ~bb;
        }
        int r = __popcll(mask & ((1ULL << ln) - 1ULL));
        rnk[i] = (unsigned char)r;
        if (r == 0) hist[s][q] = __popcll(mask);
    }
    __syncthreads();
    // per-bucket prefix over segments + bucket totals
    int cnt_tot = 0;
    if (tid < 256) {
        int tot = 0;
        #pragma unroll 8
        for (int s = 0; s < 64; ++s) { int c = hist[s][tid]; hist[s][tid] = tot; tot += c; }
        base[tid] = tot;
        cnt_tot = tot;
    }
    __syncthreads();
    // Hillis-Steele inclusive scan over 256 bucket totals
    for (int off = 1; off < 256; off <<= 1) {
        int t = (tid >= off && tid < 256) ? base[tid - off] : 0;
        __syncthreads();
        if (tid >= off && tid < 256) base[tid] += t;
        __syncthreads();
    }
    int incl = 0;
    if (tid < 256) incl = base[tid];
    __syncthreads();
    if (tid < 256) base[tid] = incl - cnt_tot;   // exclusive global base
    __syncthreads();
    // fully parallel stable scatter
    for (int i = tid; i < 4096; i += 1024) {
        int q = bkt[i];
        outg[base[q] + hist[i >> 6][q] + rnk[i]] = i;
    }
}

// ---------------- kernel 3: fused block-diag + residual attention ----------------
// grid: 1024; XCD swizzle puts all 32 g-tiles of a bh on one XCD (sampled-K/V L2 reuse)
// 512 threads (8 waves); LDS 66.5 KB -> 2 blocks/CU; (512,4): 128-VGPR budget, no spill
__global__ __launch_bounds__(512, 4) void attn_kernel(const float* __restrict__ qkv,
                                                      const int* __restrict__ sampled,
                                                      const int* __restrict__ qidx_g,
                                                      const int* __restrict__ kidx_g,
                                                      float* __restrict__ out) {
    int bid = blockIdx.x;
    int gb = (bid & 7) * 128 + (bid >> 3);   // bijective: XCD x -> bh in [4x, 4x+4)
    int bh = gb >> 5, g = gb & 31;
    int b = bh >> 4, h = bh & 15;
    int tid = threadIdx.x;
    int w = tid >> 6, l = tid & 63;
    int l15 = l & 15, lq = l >> 4;

    // KP: phase1 = K [256 rows][8 chunks], later = P half [128 rows][16 chunks]
    __shared__ us8 KP[2048];                 // 32 KB
    __shared__ us8 VT[2048];                 // 32 KB: V^T [64 dims][32 chunks] (256 keys)
    __shared__ float colbias[256];
    __shared__ int qrow[128];
    __shared__ int krow[256];

    // ---- index staging ----
    if (tid < 128) {
        qrow[tid] = qidx_g[bh * NSEQ + g * 128 + tid];
        krow[tid] = kidx_g[bh * NSEQ + g * 128 + tid];
        colbias[tid] = 0.0f;
    } else if (tid < 256) {
        int j = tid - 128;
        int sp = sampled[bh * 128 + j];
        krow[tid] = kidx_g[bh * NSEQ + sp];
        colbias[tid] = ((sp >> 7) == g) ? -1e30f : LOG32;
    }
    __syncthreads();

    // ---- Q fragments straight from global (this wave's 16 rows) ----
    int qr = qrow[w * 16 + l15];
    const float* qbase = qkv + ((size_t)((b * NSEQ + qr) * 3 + 0)) * 1024 + h * 64 + lq * 8;
    float4 qa0 = *(const float4*)(qbase);
    float4 qa1 = *(const float4*)(qbase + 4);
    float4 qb0 = *(const float4*)(qbase + 32);
    float4 qb1 = *(const float4*)(qbase + 36);

    // ---- stage K (256 rows x 64) into KP, swizzled ----
    #pragma unroll
    for (int rep = 0; rep < 2; ++rep) {
        int job = tid + rep * 512;
        int r = job >> 2, qt = job & 3;
        const float4* src = (const float4*)(qkv + ((size_t)((b * NSEQ + krow[r]) * 3 + 1)) * 1024 + h * 64 + qt * 16);
        float4 f0 = src[0], f1 = src[1], f2 = src[2], f3 = src[3];
        us8 u0 = __builtin_bit_cast(us8, cvt8(f0, f1));
        us8 u1 = __builtin_bit_cast(us8, cvt8(f2, f3));
        KP[r * 8 + ((qt * 2) ^ (r & 7))] = u0;
        KP[r * 8 + ((qt * 2 + 1) ^ (r & 7))] = u1;
    }
    // ---- stage V transposed (all 256 keys; 2 threads per key, 32 dims each), swizzled ----
    {
        int key = tid >> 1, half = tid & 1;
        const float4* src = (const float4*)(qkv + ((size_t)((b * NSEQ + krow[key]) * 3 + 2)) * 1024 + h * 64 + half * 32);
        unsigned short* vt_us = (unsigned short*)VT;
        int kc8 = key >> 3, ke = key & 7;
        #pragma unroll
        for (int d4 = 0; d4 < 8; ++d4) {
            float4 f = src[d4];
            int d = half * 32 + d4 * 4;
            vt_us[(((d + 0) * 32 + (kc8 ^ ((d + 0) & 7))) << 3) + ke] = f2b(f.x);
            vt_us[(((d + 1) * 32 + (kc8 ^ ((d + 1) & 7))) << 3) + ke] = f2b(f.y);
            vt_us[(((d + 2) * 32 + (kc8 ^ ((d + 2) & 7))) << 3) + ke] = f2b(f.z);
            vt_us[(((d + 3) * 32 + (kc8 ^ ((d + 3) & 7))) << 3) + ke] = f2b(f.w);
        }
    }
    __syncthreads();

    // ---- phase 1: S = Q K^T * scale + bias, scores stay in registers ----
    bf16x8 a0 = cvt8(qa0, qa1);
    bf16x8 a1 = cvt8(qb0, qb1);
    f32x4 sreg[16];
    #pragma unroll
    for (int ct = 0; ct < 16; ++ct) {
        int kr = ct * 16 + l15;
        bf16x8 b0 = __builtin_bit_cast(bf16x8, KP[kr * 8 + (lq ^ (kr & 7))]);
        bf16x8 b1 = __builtin_bit_cast(bf16x8, KP[kr * 8 + ((lq + 4) ^ (kr & 7))]);
        f32x4 acc = {0.f, 0.f, 0.f, 0.f};
        acc = __builtin_amdgcn_mfma_f32_16x16x32_bf16(a0, b0, acc, 0, 0, 0);
        acc = __builtin_amdgcn_mfma_f32_16x16x32_bf16(a1, b1, acc, 0, 0, 0);
        float cb = colbias[kr];
        #pragma unroll
        for (int j = 0; j < 4; ++j) sreg[ct][j] = acc[j] * QSCALE + cb;
    }

    // ---- phase 2: softmax fully in registers ----
    float m0 = -1e30f, m1 = -1e30f, m2 = -1e30f, m3 = -1e30f;
    #pragma unroll
    for (int ct = 0; ct < 16; ++ct) {
        m0 = fmaxf(m0, sreg[ct][0]); m1 = fmaxf(m1, sreg[ct][1]);
        m2 = fmaxf(m2, sreg[ct][2]); m3 = fmaxf(m3, sreg[ct][3]);
    }
    #pragma unroll
    for (int mask = 1; mask < 16; mask <<= 1) {
        m0 = fmaxf(m0, __shfl_xor(m0, mask));
        m1 = fmaxf(m1, __shfl_xor(m1, mask));
        m2 = fmaxf(m2, __shfl_xor(m2, mask));
        m3 = fmaxf(m3, __shfl_xor(m3, mask));
    }
    float s0 = 0.f, s1 = 0.f, s2 = 0.f, s3 = 0.f;
    #pragma unroll
    for (int ct = 0; ct < 16; ++ct) {
        float p0 = __expf(sreg[ct][0] - m0); sreg[ct][0] = p0; s0 += p0;
        float p1 = __expf(sreg[ct][1] - m1); sreg[ct][1] = p1; s1 += p1;
        float p2 = __expf(sreg[ct][2] - m2); sreg[ct][2] = p2; s2 += p2;
        float p3 = __expf(sreg[ct][3] - m3); sreg[ct][3] = p3; s3 += p3;
    }
    #pragma unroll
    for (int mask = 1; mask < 16; mask <<= 1) {
        s0 += __shfl_xor(s0, mask);
        s1 += __shfl_xor(s1, mask);
        s2 += __shfl_xor(s2, mask);
        s3 += __shfl_xor(s3, mask);
    }
    float rs0 = 1.f / s0, rs1 = 1.f / s1, rs2 = 1.f / s2, rs3 = 1.f / s3;

    __syncthreads();   // all waves done reading K from KP

    unsigned short* pp = (unsigned short*)KP;
    int wrow0 = w * 16 + lq * 4;
    // ---- write P-lo (cols 0..127) over KP ----
    #pragma unroll
    for (int ct = 0; ct < 8; ++ct) {
        int c8 = 2 * ct + (l15 >> 3), ce = l15 & 7;
        #pragma unroll
        for (int j = 0; j < 4; ++j) {
            int row = wrow0 + j;
            pp[((row * 16 + (c8 ^ (row & 7))) << 3) + ce] = f2b(sreg[ct][j]);
        }
    }
    __syncthreads();

    f32x4 oacc[4] = {{0.f,0.f,0.f,0.f},{0.f,0.f,0.f,0.f},{0.f,0.f,0.f,0.f},{0.f,0.f,0.f,0.f}};
    int prow = w * 16 + l15;
    // ---- PV pass 1 (keys 0..127) ----
    #pragma unroll
    for (int ks = 0; ks < 4; ++ks) {
        bf16x8 pa = __builtin_bit_cast(bf16x8, KP[prow * 16 + ((ks * 4 + lq) ^ (prow & 7))]);
        #pragma unroll
        for (int ct = 0; ct < 4; ++ct) {
            int d = ct * 16 + l15;
            bf16x8 vb = __builtin_bit_cast(bf16x8, VT[d * 32 + ((ks * 4 + lq) ^ (d & 7))]);
            oacc[ct] = __builtin_amdgcn_mfma_f32_16x16x32_bf16(pa, vb, oacc[ct], 0, 0, 0);
        }
    }
    __syncthreads();   // P-lo dead
    // ---- write P-hi (cols 128..255) over KP ----
    #pragma unroll
    for (int ct = 8; ct < 16; ++ct) {
        int c8 = 2 * (ct - 8) + (l15 >> 3), ce = l15 & 7;
        #pragma unroll
        for (int j = 0; j < 4; ++j) {
            int row = wrow0 + j;
            pp[((row * 16 + (c8 ^ (row & 7))) << 3) + ce] = f2b(sreg[ct][j]);
        }
    }
    __syncthreads();
    // ---- PV pass 2 (keys 128..255) ----
    #pragma unroll
    for (int ks = 4; ks < 8; ++ks) {
        bf16x8 pa = __builtin_bit_cast(bf16x8, KP[prow * 16 + (((ks - 4) * 4 + lq) ^ (prow & 7))]);
        #pragma unroll
        for (int ct = 0; ct < 4; ++ct) {
            int d = ct * 16 + l15;
            bf16x8 vb = __builtin_bit_cast(bf16x8, VT[d * 32 + ((ks * 4 + lq) ^ (d & 7))]);
            oacc[ct] = __builtin_amdgcn_mfma_f32_16x16x32_bf16(pa, vb, oacc[ct], 0, 0, 0);
        }
    }

    // ---- epilogue: normalize + scatter to original query positions ----
    float rs[4] = {rs0, rs1, rs2, rs3};
    #pragma unroll
    for (int j = 0; j < 4; ++j) {
        int row = wrow0 + j;
        size_t obase = ((size_t)((b * NSEQ + qrow[row]) * 16 + h)) * 64;
        #pragma unroll
        for (int ct = 0; ct < 4; ++ct)
            out[obase + ct * 16 + l15] = oacc[ct][j] * rs[j];
    }
}

extern "C" void kernel_launch(void* const* d_in, const int* in_sizes, int n_in,
                              void* d_out, int out_size, void* d_ws, size_t ws_size,
                              hipStream_t stream) {
    const float* qkv = (const float*)d_in[0];      // [2,4096,3,16,64] f32
    const float* proj = (const float*)d_in[1];     // [64,8] f32
    const int* sampled = (const int*)d_in[2];      // [2,16,128] i32
    float* outp = (float*)d_out;                   // [2,4096,16,64] f32

    int* qidx = (int*)d_ws;
    int* kidx = qidx + NBH * NSEQ;
    unsigned short* hsh = (unsigned short*)(kidx + NBH * NSEQ);

    hash_kernel<<<1024, 256, 0, stream>>>(qkv, proj, hsh);
    sort_kernel<<<64, 1024, 0, stream>>>(hsh, qidx, kidx);
    attn_kernel<<<NBH * 32, 512, 0, stream>>>(qkv, sampled, qidx, kidx, outp);
}